// Round 13
// baseline (75.730 us; speedup 1.0000x reference)
//
#include <hip/hip_runtime.h>
#include <stdint.h>

#define BATCH 256
#define INF   1024
#define OUTF  128
#define KD    8
#define NN    1024      // OUTF*KD
#define OROW  1152      // INF + OUTF

#define TSLP  1040      // Tsl row stride in shorts (2080 B row pitch)
#define MLS   12        // Mloc row stride in floats
#define CHSH  16384     // shorts per x-chunk: 256 rows x 64 bf16 = 32 KB
#define NBUF  4         // chunk buffers (3 in flight + 1 being read)

typedef __attribute__((ext_vector_type(8))) short short8;
typedef __attribute__((ext_vector_type(4))) float f32x4;

__device__ __forceinline__ unsigned short f2bf(float f) {
    union { float f; uint32_t u; } v; v.f = f;
    uint32_t r = v.u + 0x7FFFu + ((v.u >> 16) & 1u);   // RNE
    return (unsigned short)(r >> 16);
}

// K1 (R9-verified, unchanged): T transpose-convert (blocks 0..255) -> Tt[n][k]
// bf16; x copy + bf16 convert (blocks 256..319).
__global__ __launch_bounds__(256) void prep_kernel(
    const float* __restrict__ x, const float* __restrict__ T,
    float* __restrict__ out, unsigned short* __restrict__ xbf,
    unsigned short* __restrict__ Tt)
{
    __shared__ unsigned short lds[64 * 65];
    int bid = blockIdx.x;
    int t = threadIdx.x;
    if (bid < 256) {
        int i0 = (bid >> 4) << 6;          // k-block
        int n0 = (bid & 15) << 6;          // n-block
        int tx = t & 63, ty = t >> 6;
        for (int r = ty; r < 64; r += 4) {
            float v = T[(size_t)(i0 + r) * NN + n0 + tx];
            lds[tx * 65 + r] = f2bf(v);    // lds[n_local][k_local]
        }
        __syncthreads();
        #pragma unroll
        for (int p = 0; p < 8; ++p) {
            int q = p * 512 + t * 2;
            int n = q >> 6, i = q & 63;    // i even
            uint32_t u = (uint32_t)lds[n * 65 + i] | ((uint32_t)lds[n * 65 + i + 1] << 16);
            *(uint32_t*)(Tt + (size_t)(n0 + n) * INF + i0 + i) = u;
        }
    } else {
        int bx = bid - 256;                // 0..63
        #pragma unroll
        for (int p = 0; p < 4; ++p) {
            int a = bx * 4 + p;
            int j = t * 4;
            float4 v = *(const float4*)(x + (size_t)a * INF + j);
            *(float4*)(out + (size_t)a * OROW + j) = v;
            uint2 u;
            u.x = (uint32_t)f2bf(v.x) | ((uint32_t)f2bf(v.y) << 16);
            u.y = (uint32_t)f2bf(v.z) | ((uint32_t)f2bf(v.w) << 16);
            *(uint2*)(xbf + (size_t)a * INF + j) = u;
        }
    }
}

// DMA one 256x64 bf16 chunk of xbf into LDS (R9-verified). Wave-private rows.
__device__ __forceinline__ void stage_xb(
    const unsigned short* __restrict__ xbf, unsigned short* lbuf,
    int c, int wave, int lane)
{
    const int rin = lane >> 3;             // row within 8-row instr block
    const int seg = lane & 7;              // 16 B slot (8 bf16)
    #pragma unroll
    for (int p = 0; p < 4; ++p) {
        const int i = wave * 4 + p;        // instr 0..31
        const unsigned short* src = xbf + (size_t)(i * 8 + rin) * INF
                                        + c * 64 + ((seg ^ rin) << 3);
        unsigned short* dst = lbuf + i * 512;   // 1 KB per instr, linear
        __builtin_amdgcn_global_load_lds(
            (const __attribute__((address_space(1))) unsigned int*)src,
            (__attribute__((address_space(3))) unsigned int*)dst, 16, 0, 0);
    }
}

// One K=64 GEMM step (R9-verified): vmcnt gate + 6x ds_read_b128 + lgkmcnt(0)
// in ONE asm block so hipcc inserts no vmcnt(0) drain.
#define GEMM_STEP(c, VM) do {                                                 \
    const uint32_t bb = xlsBase + (uint32_t)(((c) & 3) << 15);                \
    const uint32_t tb = tslBase + (uint32_t)((c) << 7);                       \
    short8 A00, A01, A10, A11, B0, B1;                                        \
    asm volatile(                                                             \
        "s_waitcnt vmcnt(" #VM ")\n\t"                                        \
        "ds_read_b128 %0, %6\n\t"                                             \
        "ds_read_b128 %1, %7\n\t"                                             \
        "ds_read_b128 %2, %8\n\t"                                             \
        "ds_read_b128 %3, %9\n\t"                                             \
        "ds_read_b128 %4, %10\n\t"                                            \
        "ds_read_b128 %5, %11\n\t"                                            \
        "s_waitcnt lgkmcnt(0)"                                                \
        : "=v"(A00), "=v"(A01), "=v"(A10), "=v"(A11), "=v"(B0), "=v"(B1)      \
        : "v"(bb + oA00), "v"(bb + oA01), "v"(bb + oA10), "v"(bb + oA11),     \
          "v"(tb + oB0), "v"(tb + oB1)                                        \
        : "memory");                                                          \
    acc0 = __builtin_amdgcn_mfma_f32_16x16x32_bf16(A00, B0, acc0, 0, 0, 0);   \
    acc0 = __builtin_amdgcn_mfma_f32_16x16x32_bf16(A01, B1, acc0, 0, 0, 0);   \
    acc1 = __builtin_amdgcn_mfma_f32_16x16x32_bf16(A10, B0, acc1, 0, 0, 0);   \
    acc1 = __builtin_amdgcn_mfma_f32_16x16x32_bf16(A11, B1, acc1, 0, 0, 0);   \
} while (0)

// K2 (ABLATION build of the R9 kernel): GEMM+staging region runs TWICE with
// the identical vmcnt schedule; every product accumulates twice; epilogue
// scales by 0.5f (exact in fp32). Single variable vs R9: GEMM trip count.
__global__ __launch_bounds__(512, 1) void fused_kernel(
    const unsigned short* __restrict__ xbf, const unsigned short* __restrict__ Tt,
    float* __restrict__ out)
{
    __shared__ __align__(16) unsigned short xls[NBUF * CHSH];   // 128 KB
    __shared__ __align__(16) union {
        unsigned short Tsl[KD * TSLP];                          // 16.25 KB (GEMM)
        float red[512];                                         // 2 KB (pair)
    } u;
    __shared__ __align__(16) float Mloc[256 * MLS];             // 12 KB

    const int o = blockIdx.x >> 1;
    const int half = blockIdx.x & 1;
    const int t = threadIdx.x;
    const int wave = t >> 6, lane = t & 63;

    // Stage Tsl: Tt rows 8o..8o+8 (2 instrs/wave; kd = wave).
    #pragma unroll
    for (int p = 0; p < 2; ++p) {
        const unsigned short* src = Tt + (size_t)(o * 8 + wave) * INF + p * 512 + lane * 8;
        unsigned short* dst = u.Tsl + wave * TSLP + p * 512;
        __builtin_amdgcn_global_load_lds(
            (const __attribute__((address_space(1))) unsigned int*)src,
            (__attribute__((address_space(3))) unsigned int*)dst, 16, 0, 0);
    }
    __syncthreads();   // Tsl landed (cross-wave shared); outstanding = 0

    const int rc = lane & 15, quad = lane >> 4, r7 = rc & 7;
    const int abase = wave * 32;
    f32x4 acc0 = {0.f, 0.f, 0.f, 0.f}, acc1 = {0.f, 0.f, 0.f, 0.f};

    const uint32_t xlsBase = (uint32_t)(uintptr_t)(&xls[0]);
    const uint32_t tslBase = (uint32_t)(uintptr_t)(&u.Tsl[0]);
    const uint32_t rowA = (uint32_t)((abase + rc) * 128);
    const uint32_t oA00 = rowA + (uint32_t)(((0 * 4 + quad) ^ r7) << 4);
    const uint32_t oA01 = rowA + (uint32_t)(((1 * 4 + quad) ^ r7) << 4);
    const uint32_t oA10 = oA00 + 2048, oA11 = oA01 + 2048;
    const uint32_t oB0 = (uint32_t)(r7 * 2080 + quad * 16);
    const uint32_t oB1 = oB0 + 64;

    // ---- GEMM region x2 (ablation). Per rep: stage 0..2, then the R9 loop.
    // vmcnt accounting is identical in both reps (outstanding=0 at rep entry;
    // buffer reuse safe: rep's stage of buffer b issues after the program-order
    // lgkmcnt(0) of the last read of b).
    for (int rep = 0; rep < 2; ++rep) {
        stage_xb(xbf, xls + 0 * CHSH, 0, wave, lane);
        stage_xb(xbf, xls + 1 * CHSH, 1, wave, lane);
        stage_xb(xbf, xls + 2 * CHSH, 2, wave, lane);
        for (int c = 0; c < 13; ++c) {
            stage_xb(xbf, xls + ((c + 3) & 3) * CHSH, c + 3, wave, lane);
            GEMM_STEP(c, 12);          // 16 outstanding -> chunk c landed
        }
        GEMM_STEP(13, 8);
        GEMM_STEP(14, 4);
        GEMM_STEP(15, 0);
    }

    // C/D layout: col = lane&15 (= kd, valid rc<8), row = quad*4 + r [m89/m91]
    if (rc < 8) {
        #pragma unroll
        for (int r = 0; r < 4; ++r) {
            Mloc[(abase + quad * 4 + r) * MLS + rc]      = acc0[r] * 0.5f;
            Mloc[(abase + 16 + quad * 4 + r) * MLS + rc] = acc1[r] * 0.5f;
        }
    }
    __syncthreads();   // Mloc ready; Tsl dead (union -> red)

    // ---- Pair phase (R9-verified): 128 a-rows x all 256 b ----
    const int ar = t & 127;            // a-row within half
    const int bq = t >> 7;             // 0..3, wave-uniform -> LDS broadcast
    const int a = half * 128 + ar;
    f32x4 m0 = *(const f32x4*)(Mloc + a * MLS);
    f32x4 m1 = *(const f32x4*)(Mloc + a * MLS + 4);
    float ssum = 0.f;
    #pragma unroll 4
    for (int j = 0; j < 64; ++j) {
        const float* qp = Mloc + (bq * 64 + j) * MLS;
        f32x4 q0 = *(const f32x4*)(qp);
        f32x4 q1 = *(const f32x4*)(qp + 4);
        float d = fabsf(m0[0] - q0[0]) + fabsf(m0[1] - q0[1])
                + fabsf(m0[2] - q0[2]) + fabsf(m0[3] - q0[3])
                + fabsf(m1[0] - q1[0]) + fabsf(m1[1] - q1[1])
                + fabsf(m1[2] - q1[2]) + fabsf(m1[3] - q1[3]);
        ssum += __expf(-d);
    }
    u.red[t] = ssum;
    __syncthreads();
    if (t < 128) {
        float s = u.red[t] + u.red[t + 128] + u.red[t + 256] + u.red[t + 384];
        out[(size_t)(half * 128 + t) * OROW + INF + o] = s - 1.0f;  // -1 = self term
    }
}

extern "C" void kernel_launch(void* const* d_in, const int* in_sizes, int n_in,
                              void* d_out, int out_size, void* d_ws, size_t ws_size,
                              hipStream_t stream) {
    const float* x = (const float*)d_in[0];
    const float* T = (const float*)d_in[1];
    float* out = (float*)d_out;
    unsigned short* xbf = (unsigned short*)d_ws;                       // 512 KB
    unsigned short* Tt  = (unsigned short*)((char*)d_ws + 524288);     // 2 MB

    prep_kernel<<<320, 256, 0, stream>>>(x, T, out, xbf, Tt);
    fused_kernel<<<256, 512, 0, stream>>>(xbf, Tt, out);
}

// Round 14
// 70.741 us; speedup vs baseline: 1.0705x; 1.0705x over previous
//
#include <hip/hip_runtime.h>
#include <stdint.h>

#define BATCH 256
#define INF   1024
#define OUTF  128
#define KD    8
#define NN    1024      // OUTF*KD
#define OROW  1152      // INF + OUTF

#define TSLP  1040      // Tsl row stride in shorts (2080 B row pitch)
#define MLS   12        // Mloc row stride in floats
#define CHSH  16384     // shorts per x-chunk: 256 rows x 64 bf16 = 32 KB
#define NBUF  4         // chunk buffers (3 in flight + 1 being read)

typedef __attribute__((ext_vector_type(8))) short short8;
typedef __attribute__((ext_vector_type(4))) float f32x4;

__device__ __forceinline__ unsigned short f2bf(float f) {
    union { float f; uint32_t u; } v; v.f = f;
    uint32_t r = v.u + 0x7FFFu + ((v.u >> 16) & 1u);   // RNE
    return (unsigned short)(r >> 16);
}

// K1 (R9-verified, unchanged): T transpose-convert (blocks 0..255) -> Tt[n][k]
// bf16; x copy + bf16 convert (blocks 256..319).
__global__ __launch_bounds__(256) void prep_kernel(
    const float* __restrict__ x, const float* __restrict__ T,
    float* __restrict__ out, unsigned short* __restrict__ xbf,
    unsigned short* __restrict__ Tt)
{
    __shared__ unsigned short lds[64 * 65];
    int bid = blockIdx.x;
    int t = threadIdx.x;
    if (bid < 256) {
        int i0 = (bid >> 4) << 6;          // k-block
        int n0 = (bid & 15) << 6;          // n-block
        int tx = t & 63, ty = t >> 6;
        for (int r = ty; r < 64; r += 4) {
            float v = T[(size_t)(i0 + r) * NN + n0 + tx];
            lds[tx * 65 + r] = f2bf(v);    // lds[n_local][k_local]
        }
        __syncthreads();
        #pragma unroll
        for (int p = 0; p < 8; ++p) {
            int q = p * 512 + t * 2;
            int n = q >> 6, i = q & 63;    // i even
            uint32_t u = (uint32_t)lds[n * 65 + i] | ((uint32_t)lds[n * 65 + i + 1] << 16);
            *(uint32_t*)(Tt + (size_t)(n0 + n) * INF + i0 + i) = u;
        }
    } else {
        int bx = bid - 256;                // 0..63
        #pragma unroll
        for (int p = 0; p < 4; ++p) {
            int a = bx * 4 + p;
            int j = t * 4;
            float4 v = *(const float4*)(x + (size_t)a * INF + j);
            *(float4*)(out + (size_t)a * OROW + j) = v;
            uint2 u;
            u.x = (uint32_t)f2bf(v.x) | ((uint32_t)f2bf(v.y) << 16);
            u.y = (uint32_t)f2bf(v.z) | ((uint32_t)f2bf(v.w) << 16);
            *(uint2*)(xbf + (size_t)a * INF + j) = u;
        }
    }
}

// DMA this wave's 16 rows of one 256x64 bf16 chunk (2 instrs/wave). Wave w
// stages rows [16w,16w+16) -> LDS bytes [2KB*w,2KB*(w+1)) and reads only
// those rows: wave-private pipeline, no barrier. seg^(row&7) XOR on the
// GLOBAL source (m173) so swizzled b128 LDS reads are bank-clean.
__device__ __forceinline__ void stage_xb(
    const unsigned short* __restrict__ xbf, unsigned short* lbuf,
    int c, int wave, int lane)
{
    const int rin = lane >> 3;             // row within 8-row instr block
    const int seg = lane & 7;              // 16 B slot (8 bf16)
    #pragma unroll
    for (int p = 0; p < 2; ++p) {
        const int i = wave * 2 + p;        // instr 0..31
        const unsigned short* src = xbf + (size_t)(i * 8 + rin) * INF
                                        + c * 64 + ((seg ^ rin) << 3);
        unsigned short* dst = lbuf + i * 512;   // 1 KB per instr, linear
        __builtin_amdgcn_global_load_lds(
            (const __attribute__((address_space(1))) unsigned int*)src,
            (__attribute__((address_space(3))) unsigned int*)dst, 16, 0, 0);
    }
}

// One K=64 GEMM step (16-wave variant of the R9-verified step): vmcnt gate +
// 4x ds_read_b128 + lgkmcnt(0) in ONE asm block so hipcc inserts no vmcnt(0)
// drain. Two MFMAs into INDEPENDENT accumulators (no intra-step chain).
#define GEMM_STEP(c, VM) do {                                                 \
    const uint32_t bb = xlsBase + (uint32_t)(((c) & 3) << 15);                \
    const uint32_t tb = tslBase + (uint32_t)((c) << 7);                       \
    short8 A0, A1, B0, B1;                                                    \
    asm volatile(                                                             \
        "s_waitcnt vmcnt(" #VM ")\n\t"                                        \
        "ds_read_b128 %0, %4\n\t"                                             \
        "ds_read_b128 %1, %5\n\t"                                             \
        "ds_read_b128 %2, %6\n\t"                                             \
        "ds_read_b128 %3, %7\n\t"                                             \
        "s_waitcnt lgkmcnt(0)"                                                \
        : "=v"(A0), "=v"(A1), "=v"(B0), "=v"(B1)                              \
        : "v"(bb + oA0), "v"(bb + oA1), "v"(tb + oB0), "v"(tb + oB1)          \
        : "memory");                                                          \
    acc0 = __builtin_amdgcn_mfma_f32_16x16x32_bf16(A0, B0, acc0, 0, 0, 0);    \
    acc1 = __builtin_amdgcn_mfma_f32_16x16x32_bf16(A1, B1, acc1, 0, 0, 0);    \
} while (0)

// K2: 256 blocks = (o, a-half), 1024 threads = 16 waves (4/SIMD TLP).
// GEMM: wave w owns M rows [16w,16w+16). Pair: 8-way b-split, 32 iters/thread.
__global__ __launch_bounds__(1024, 1) void fused_kernel(
    const unsigned short* __restrict__ xbf, const unsigned short* __restrict__ Tt,
    float* __restrict__ out)
{
    __shared__ __align__(16) unsigned short xls[NBUF * CHSH];   // 128 KB
    __shared__ __align__(16) union {
        unsigned short Tsl[KD * TSLP];                          // 16.25 KB (GEMM)
        float red[1024];                                        // 4 KB (pair)
    } u;
    __shared__ __align__(16) float Mloc[256 * MLS];             // 12 KB
    // total 160000 B <= 160 KiB -> 1 block/CU

    const int o = blockIdx.x >> 1;
    const int half = blockIdx.x & 1;
    const int t = threadIdx.x;
    const int wave = t >> 6, lane = t & 63;

    // Stage Tsl: waves 0..7 load Tt rows 8o..8o+8 (2 instrs each; kd = wave).
    if (wave < 8) {
        #pragma unroll
        for (int p = 0; p < 2; ++p) {
            const unsigned short* src = Tt + (size_t)(o * 8 + wave) * INF + p * 512 + lane * 8;
            unsigned short* dst = u.Tsl + wave * TSLP + p * 512;
            __builtin_amdgcn_global_load_lds(
                (const __attribute__((address_space(1))) unsigned int*)src,
                (__attribute__((address_space(3))) unsigned int*)dst, 16, 0, 0);
        }
    }
    // Prologue: chunks 0..2 (depth-3; drained once by the entry barrier).
    stage_xb(xbf, xls + 0 * CHSH, 0, wave, lane);
    stage_xb(xbf, xls + 1 * CHSH, 1, wave, lane);
    stage_xb(xbf, xls + 2 * CHSH, 2, wave, lane);
    __syncthreads();   // Tsl + chunks 0..2 landed; outstanding = 0 per wave

    // ---- GEMM: 16 K-chunks, 2 DMA instrs/wave/chunk, depth-3 ----
    const int rc = lane & 15, quad = lane >> 4, r7 = rc & 7;
    f32x4 acc0 = {0.f, 0.f, 0.f, 0.f}, acc1 = {0.f, 0.f, 0.f, 0.f};

    const uint32_t xlsBase = (uint32_t)(uintptr_t)(&xls[0]);
    const uint32_t tslBase = (uint32_t)(uintptr_t)(&u.Tsl[0]);
    const uint32_t rowA = (uint32_t)((wave * 16 + rc) * 128);
    const uint32_t oA0 = rowA + (uint32_t)(((0 * 4 + quad) ^ r7) << 4);  // k 0..31
    const uint32_t oA1 = rowA + (uint32_t)(((1 * 4 + quad) ^ r7) << 4);  // k 32..63
    const uint32_t oB0 = (uint32_t)(r7 * 2080 + quad * 16);
    const uint32_t oB1 = oB0 + 64;

    for (int c = 0; c < 13; ++c) {
        stage_xb(xbf, xls + ((c + 3) & 3) * CHSH, c + 3, wave, lane);
        GEMM_STEP(c, 6);               // 8 outstanding -> chunk c landed
    }
    GEMM_STEP(13, 4);
    GEMM_STEP(14, 2);
    GEMM_STEP(15, 0);

    // C/D layout: col = lane&15 (= kd, valid rc<8), row = quad*4 + r [m89/m91]
    if (rc < 8) {
        #pragma unroll
        for (int r = 0; r < 4; ++r)
            Mloc[(wave * 16 + quad * 4 + r) * MLS + rc] = acc0[r] + acc1[r];
    }
    __syncthreads();   // Mloc ready; Tsl dead (union -> red)

    // ---- Pair phase: this block's 128 a-rows x all 256 b (8-way b-split) ----
    const int ar = t & 127;            // a-row within half
    const int bq = t >> 7;             // 0..7, wave-uniform -> LDS broadcast
    const int a = half * 128 + ar;
    f32x4 m0 = *(const f32x4*)(Mloc + a * MLS);
    f32x4 m1 = *(const f32x4*)(Mloc + a * MLS + 4);
    float ssum = 0.f;
    #pragma unroll 4
    for (int j = 0; j < 32; ++j) {
        const float* qp = Mloc + (bq * 32 + j) * MLS;
        f32x4 q0 = *(const f32x4*)(qp);
        f32x4 q1 = *(const f32x4*)(qp + 4);
        float d = fabsf(m0[0] - q0[0]) + fabsf(m0[1] - q0[1])
                + fabsf(m0[2] - q0[2]) + fabsf(m0[3] - q0[3])
                + fabsf(m1[0] - q1[0]) + fabsf(m1[1] - q1[1])
                + fabsf(m1[2] - q1[2]) + fabsf(m1[3] - q1[3]);
        ssum += __expf(-d);
    }
    u.red[t] = ssum;
    __syncthreads();
    if (t < 128) {
        float s = 0.f;
        #pragma unroll
        for (int q = 0; q < 8; ++q) s += u.red[t + q * 128];
        out[(size_t)(half * 128 + t) * OROW + INF + o] = s - 1.0f;  // -1 = self term
    }
}

extern "C" void kernel_launch(void* const* d_in, const int* in_sizes, int n_in,
                              void* d_out, int out_size, void* d_ws, size_t ws_size,
                              hipStream_t stream) {
    const float* x = (const float*)d_in[0];
    const float* T = (const float*)d_in[1];
    float* out = (float*)d_out;
    unsigned short* xbf = (unsigned short*)d_ws;                       // 512 KB
    unsigned short* Tt  = (unsigned short*)((char*)d_ws + 524288);     // 2 MB

    prep_kernel<<<320, 256, 0, stream>>>(x, T, out, xbf, Tt);
    fused_kernel<<<256, 1024, 0, stream>>>(xbf, Tt, out);
}